// Round 22
// baseline (104.996 us; speedup 1.0000x reference)
//
#include <hip/hip_runtime.h>
#include <math.h>

#define CIN 64
#define NP 128

typedef float f32x4 __attribute__((ext_vector_type(4)));
typedef short s16x8 __attribute__((ext_vector_type(8)));
typedef short s16x4 __attribute__((ext_vector_type(4)));

union FragU { s16x8 v; unsigned u[4]; };
union Frag4 { s16x4 v; unsigned u[2]; };

static __device__ __forceinline__ unsigned short f2b(float f) {
    unsigned u = __builtin_bit_cast(unsigned, f);
    unsigned r = (u + 0x7FFFu + ((u >> 16) & 1u)) >> 16;   // RNE (proven R1/R2/R5/R8)
    return (unsigned short)r;
}
// pack two f32 -> bf16x2 word, software RNE — NOT v_cvt_pk (R6: raw instr != RNE)
static __device__ __forceinline__ unsigned pack2(float lo, float hi) {
    return (unsigned)f2b(lo) | ((unsigned)f2b(hi) << 16);
}

// 16x16x16 bf16 MFMA (gfx950 instruction per ISA §10; proven R14-R21)
static __device__ __forceinline__ f32x4 mfma16(s16x4 a, s16x4 b, f32x4 c) {
#if __has_builtin(__builtin_amdgcn_mfma_f32_16x16x16bf16_1k)
    return __builtin_amdgcn_mfma_f32_16x16x16bf16_1k(a, b, c, 0, 0, 0);
#else
    asm volatile("v_mfma_f32_16x16x16_bf16 %0, %1, %2, %0\n\ts_nop 7\n\ts_nop 7"
                 : "+v"(c) : "v"(a), "v"(b));
    return c;
#endif
}

// K0: pack W_k, W_v (rows 128..383 of Wqkv) into bf16 MFMA fragment tiles.
__global__ __launch_bounds__(256) void prep_w(const float* __restrict__ Wqkv,
                                              unsigned short* __restrict__ Wb) {
    int e0 = (blockIdx.x * 256 + threadIdx.x) * 8;   // < 16384
    int lane = (e0 >> 3) & 63;
    int kc = (e0 >> 9) & 1;
    int t = e0 >> 10;
    int row = 128 + t * 16 + (lane & 15);
    int c0 = kc * 32 + (lane >> 4) * 8;
    for (int j = 0; j < 8; ++j)
        Wb[e0 + j] = f2b(Wqkv[row * 64 + c0 + j]);
}

// K1: fused kv-projection + exp + context, all in registers; TWO heads/block,
// K/V phase-split (R17/R18). R22 change: __launch_bounds__(256,3) — the
// phase-split kernel measures 108 VGPR + 32 AGPR = 140 unified regs, which
// FITS the (256,3) cap of ~170 (R16's spill at (256,3) was the pre-split
// kernel). 12 waves/CU vs the 8 that R18-R20 were self-capped at while
// latency-bound. Grid 864 blocks = 3.4/CU, so the 3rd block slot fills.
__global__ __launch_bounds__(256, 3) void lin_attn_ctx(
    const float* __restrict__ x, const unsigned short* __restrict__ Wb,
    float* __restrict__ P, int n, int nch)
{
    __shared__ float RED[4224];          // epilogue-only: 4x1024 ctx + 4x32 sums

    const int tid = threadIdx.x;
    const int l = tid & 63;
    const int w = tid >> 6;
    const int h0 = blockIdx.x * 2;       // head pair (fastest)
    const int b = blockIdx.y;            // batch
    const int slot = blockIdx.z;         // chunk slot
    const int nslot = gridDim.z;
    const int l15 = l & 15, lg = l >> 4;
    const uint4* Wb4 = (const uint4*)Wb;

    f32x4 zero4 = {0.f, 0.f, 0.f, 0.f};
    f32x4 ctx[2][2][2];                  // [hh][rt][vt]
    float sacc[2][2] = {{0.f, 0.f}, {0.f, 0.f}};
#pragma unroll
    for (int hh = 0; hh < 2; ++hh)
#pragma unroll
        for (int a = 0; a < 2; ++a)
#pragma unroll
            for (int c2 = 0; c2 < 2; ++c2) ctx[hh][a][c2] = zero4;

    const float* xw = x + (size_t)b * CIN * n + w * 32 + l15;

    for (int ch = slot; ch < nch; ch += nslot) {
        // ---- direct global -> X-fragment loads, pack immediately ----
        const float* xp = xw + ch * NP;
        s16x8 bx[2][2];
#pragma unroll
        for (int pt = 0; pt < 2; ++pt)
#pragma unroll
            for (int kc = 0; kc < 2; ++kc) {
                float xv[8];
#pragma unroll
                for (int j = 0; j < 8; ++j)
                    xv[j] = xp[(size_t)(kc * 32 + lg * 8 + j) * n + pt * 16];
                FragU fu;
#pragma unroll
                for (int i = 0; i < 4; ++i)
                    fu.u[i] = pack2(xv[2 * i], xv[2 * i + 1]);
                bx[pt][kc] = fu.v;
            }

#pragma unroll
        for (int hh = 0; hh < 2; ++hh) {
            const int h = h0 + hh;
            Frag4 ekf[2][2], vf[2][2];       // [pt][rt]
            // ---- K phase: only ak fragments live ----
            {
                s16x8 ak[2][2];
#pragma unroll
                for (int rt = 0; rt < 2; ++rt)
#pragma unroll
                    for (int kc = 0; kc < 2; ++kc)
                        ak[rt][kc] = *(const s16x8*)&Wb4[((2 * h + rt) * 2 + kc) * 64 + l];
#pragma unroll
                for (int pt = 0; pt < 2; ++pt)
#pragma unroll
                    for (int rt = 0; rt < 2; ++rt) {
                        f32x4 z = zero4;
                        z = __builtin_amdgcn_mfma_f32_16x16x32_bf16(bx[pt][0], ak[rt][0], z, 0, 0, 0);
                        z = __builtin_amdgcn_mfma_f32_16x16x32_bf16(bx[pt][1], ak[rt][1], z, 0, 0, 0);
                        float e0 = __expf(z[0]), e1 = __expf(z[1]);
                        float e2 = __expf(z[2]), e3 = __expf(z[3]);
                        sacc[hh][rt] += (e0 + e1) + (e2 + e3);
                        Frag4 fe; fe.u[0] = pack2(e0, e1); fe.u[1] = pack2(e2, e3);
                        ekf[pt][rt] = fe;
                    }
            }
            __builtin_amdgcn_sched_barrier(0);   // keep av loads out of K phase
            // ---- V phase: only av fragments live ----
            {
                s16x8 av[2][2];
#pragma unroll
                for (int rt = 0; rt < 2; ++rt)
#pragma unroll
                    for (int kc = 0; kc < 2; ++kc)
                        av[rt][kc] = *(const s16x8*)&Wb4[((8 + 2 * h + rt) * 2 + kc) * 64 + l];
#pragma unroll
                for (int pt = 0; pt < 2; ++pt)
#pragma unroll
                    for (int rt = 0; rt < 2; ++rt) {
                        f32x4 z2 = zero4;
                        z2 = __builtin_amdgcn_mfma_f32_16x16x32_bf16(bx[pt][0], av[rt][0], z2, 0, 0, 0);
                        z2 = __builtin_amdgcn_mfma_f32_16x16x32_bf16(bx[pt][1], av[rt][1], z2, 0, 0, 0);
                        Frag4 fv; fv.u[0] = pack2(z2[0], z2[1]); fv.u[1] = pack2(z2[2], z2[3]);
                        vf[pt][rt] = fv;
                    }
            }
            // ---- context: ctx[hh][rt][vt] += EK x V^T, K=pos ----
#pragma unroll
            for (int rt = 0; rt < 2; ++rt)
#pragma unroll
                for (int vt = 0; vt < 2; ++vt) {
                    ctx[hh][rt][vt] = mfma16(ekf[0][rt].v, vf[0][vt].v, ctx[hh][rt][vt]);
                    ctx[hh][rt][vt] = mfma16(ekf[1][rt].v, vf[1][vt].v, ctx[hh][rt][vt]);
                }
        }
    }

    // ---- cross-wave reduce, write both heads' partials ----
    float* Xf = RED;
    float* Sf = RED + 4096;
    float* Pb = P + (size_t)(b * nslot + slot) * 4224;
#pragma unroll
    for (int hh = 0; hh < 2; ++hh) {
        const int h = h0 + hh;
        __syncthreads();   // hh=0: trivial; hh=1: all waves done reading Xf
#pragma unroll
        for (int rt = 0; rt < 2; ++rt)
#pragma unroll
            for (int vt = 0; vt < 2; ++vt)
#pragma unroll
                for (int r = 0; r < 4; ++r) {
                    int d = rt * 16 + lg * 4 + r, e = vt * 16 + l15;
                    Xf[w * 1024 + d * 32 + e] = ctx[hh][rt][vt][r];
                }
#pragma unroll
        for (int rt = 0; rt < 2; ++rt) {
            float s = sacc[hh][rt];
            s += __shfl_xor(s, 16);
            s += __shfl_xor(s, 32);
            if (l < 16) Sf[w * 32 + rt * 16 + l15] = s;
        }
        __syncthreads();
        for (int i = tid; i < 1024; i += 256)
            Pb[h * 1056 + i] = Xf[i] + Xf[1024 + i] + Xf[2048 + i] + Xf[3072 + i];
        if (tid < 32)
            Pb[h * 1056 + 1024 + tid] = Sf[tid] + Sf[32 + tid] + Sf[64 + tid] + Sf[96 + tid];
    }
}

// K2: slot-sliced partial reduce: P[b][slot][4224] -> P2[b][16][4224]
__global__ __launch_bounds__(256) void reduce_p1(
    const float* __restrict__ P, float* __restrict__ P2, int nblk)
{
    const int idx = blockIdx.x * 256 + threadIdx.x;
    if (idx >= 4224) return;
    const int b = blockIdx.z, sz = blockIdx.y;
    float acc = 0.f;
    for (int slot = sz; slot < nblk; slot += 16)
        acc += P[((size_t)(b * nblk + slot)) * 4224 + idx];
    P2[((size_t)(b * 16 + sz)) * 4224 + idx] = acc;
}

// K3: final 16-slot reduce (merged) + build Mt[c][o]; (o-slice=8, batch) blocks.
__global__ __launch_bounds__(256) void build_M(
    const float* __restrict__ P2, const float* __restrict__ Wout,
    const float* __restrict__ Wqkv, float* __restrict__ Mt)
{
    __shared__ float Rsh[4224];
    __shared__ float ctx[4096];          // [h][e][d] (transposed)
    __shared__ float Ash[8 * 128];       // A[oo][h*32+d]
    const int b = blockIdx.y;
    const int o0 = blockIdx.x * 8;
    const int tid = threadIdx.x;
    for (int i = tid; i < 4224; i += 256) {
        float acc = 0.f;
#pragma unroll
        for (int s = 0; s < 16; ++s)
            acc += P2[((size_t)(b * 16 + s)) * 4224 + i];
        Rsh[i] = acc;
    }
    __syncthreads();
    for (int i = tid; i < 4096; i += 256) {
        const int hh = i >> 10, rr = i & 1023, e = rr >> 5, d = rr & 31;
        ctx[i] = Rsh[hh * 1056 + d * 32 + e] / Rsh[hh * 1056 + 1024 + d];
    }
    __syncthreads();
    for (int i = tid; i < 1024; i += 256) {
        const int oo = i >> 7, m = i & 127, hh = m >> 5, d = m & 31;
        float acc = 0.f;
#pragma unroll
        for (int e = 0; e < 32; ++e)
            acc += Wout[(o0 + oo) * 128 + hh * 32 + e] * ctx[hh * 1024 + e * 32 + d];
        Ash[i] = acc;
    }
    __syncthreads();
    const float scale = 0.17677669529663687f;
    for (int i = tid; i < 512; i += 256) {
        const int oo = i >> 6, c = i & 63;
        float acc = 0.f;
#pragma unroll
        for (int m = 0; m < 128; ++m)
            acc += Ash[oo * 128 + m] * Wqkv[m * 64 + c];
        Mt[b * 4096 + c * 64 + (o0 + oo)] = acc * scale;   // transposed store
    }
}

// K4: y[b,o,p] = sum_c Mt[c][o] x[b,c,p] + b_out[o]
__global__ __launch_bounds__(256, 4) void final_proj(
    const float* __restrict__ x, const float* __restrict__ Mt,
    const float* __restrict__ bout, float* __restrict__ y, int n)
{
    const int b = blockIdx.y;
    const int p = blockIdx.x * 256 + threadIdx.x;
    const float* xb = x + (size_t)b * CIN * n + p;
    const float* M = Mt + b * 4096;
    float acc[64];
#pragma unroll
    for (int o = 0; o < 64; ++o) acc[o] = bout[o];
    for (int c = 0; c < 64; ++c) {
        const float xv = xb[(size_t)c * n];
        const float* Mr = M + c * 64;
#pragma unroll
        for (int o = 0; o < 64; ++o) acc[o] += Mr[o] * xv;
    }
    float* yb = y + (size_t)b * CIN * n + p;
#pragma unroll
    for (int o = 0; o < 64; ++o) yb[(size_t)o * n] = acc[o];
}

extern "C" void kernel_launch(void* const* d_in, const int* in_sizes, int n_in,
                              void* d_out, int out_size, void* d_ws, size_t ws_size,
                              hipStream_t stream) {
    const float* x    = (const float*)d_in[0];
    const float* Wqkv = (const float*)d_in[1];
    const float* Wout = (const float*)d_in[2];
    const float* bout = (const float*)d_in[3];
    float* y = (float*)d_out;

    const int n = in_sizes[0] / 128;   // 110592
    const int nch = n / NP;            // 864

    // ws-adaptive partial-slot count (216 -> 4 chunks/block)
    int BLKX = 216;
    for (;;) {
        size_t need = 32768 + (size_t)2 * BLKX * 4224 * 4   // P
                    + (size_t)2 * 16 * 4224 * 4             // P2
                    + 2 * 4096 * 4;                         // Mt
        if (need <= ws_size || BLKX <= 64) break;
        BLKX >>= 1;
    }
    unsigned short* Wb = (unsigned short*)d_ws;                  // 32 KiB
    float* P  = (float*)((char*)d_ws + 32768);
    float* P2 = P + (size_t)2 * BLKX * 4224;
    float* Mt = P2 + (size_t)2 * 16 * 4224;

    prep_w<<<8, 256, 0, stream>>>(Wqkv, Wb);
    lin_attn_ctx<<<dim3(2, 2, BLKX), 256, 0, stream>>>(x, Wb, P, n, nch);
    reduce_p1<<<dim3(17, 16, 2), 256, 0, stream>>>(P, P2, BLKX);
    build_M<<<dim3(8, 2), 256, 0, stream>>>(P2, Wout, Wqkv, Mt);
    final_proj<<<dim3(n / 256, 2), 256, 0, stream>>>(x, Mt, bout, y, n);
}

// Round 23
// 86.734 us; speedup vs baseline: 1.2105x; 1.2105x over previous
//
#include <hip/hip_runtime.h>
#include <math.h>

#define CIN 64
#define NP 128

typedef float f32x4 __attribute__((ext_vector_type(4)));
typedef short s16x8 __attribute__((ext_vector_type(8)));
typedef short s16x4 __attribute__((ext_vector_type(4)));

union FragU { s16x8 v; unsigned u[4]; };
union Frag4 { s16x4 v; unsigned u[2]; };

static __device__ __forceinline__ unsigned short f2b(float f) {
    unsigned u = __builtin_bit_cast(unsigned, f);
    unsigned r = (u + 0x7FFFu + ((u >> 16) & 1u)) >> 16;   // RNE (proven R1/R2/R5/R8)
    return (unsigned short)r;
}
// pack two f32 -> bf16x2 word, software RNE — NOT v_cvt_pk (R6: raw instr != RNE)
static __device__ __forceinline__ unsigned pack2(float lo, float hi) {
    return (unsigned)f2b(lo) | ((unsigned)f2b(hi) << 16);
}

// 16x16x16 bf16 MFMA (gfx950 instruction per ISA §10; proven R14-R22)
static __device__ __forceinline__ f32x4 mfma16(s16x4 a, s16x4 b, f32x4 c) {
#if __has_builtin(__builtin_amdgcn_mfma_f32_16x16x16bf16_1k)
    return __builtin_amdgcn_mfma_f32_16x16x16bf16_1k(a, b, c, 0, 0, 0);
#else
    asm volatile("v_mfma_f32_16x16x16_bf16 %0, %1, %2, %0\n\ts_nop 7\n\ts_nop 7"
                 : "+v"(c) : "v"(a), "v"(b));
    return c;
#endif
}

// K0: pack W_k, W_v (rows 128..383 of Wqkv) into bf16 MFMA fragment tiles.
__global__ __launch_bounds__(256) void prep_w(const float* __restrict__ Wqkv,
                                              unsigned short* __restrict__ Wb) {
    int e0 = (blockIdx.x * 256 + threadIdx.x) * 8;   // < 16384
    int lane = (e0 >> 3) & 63;
    int kc = (e0 >> 9) & 1;
    int t = e0 >> 10;
    int row = 128 + t * 16 + (lane & 15);
    int c0 = kc * 32 + (lane >> 4) * 8;
    for (int j = 0; j < 8; ++j)
        Wb[e0 + j] = f2b(Wqkv[row * 64 + c0 + j]);
}

// K1: fused kv-projection + exp + context, all in registers; TWO heads/block
// at __launch_bounds__(256,2) — LOCKED (R8/R16/R22: (256,3) always spills).
// R23 change: CHUNK-PAIR ILP — the 4 chunks/block are processed as 2 pairs
// with fully interleaved A/B compute streams (pack, proj-MFMA, exp, ctx).
// At 2 waves/SIMD (occupancy cap), two independent dependency chains per
// wave fill the latency stalls that kept VALUBusy at 27% (R18-R20 plateau).
__global__ __launch_bounds__(256, 2) void lin_attn_ctx(
    const float* __restrict__ x, const unsigned short* __restrict__ Wb,
    float* __restrict__ P, int n, int nch)
{
    __shared__ float RED[4224];          // epilogue-only: 4x1024 ctx + 4x32 sums

    const int tid = threadIdx.x;
    const int l = tid & 63;
    const int w = tid >> 6;
    const int h0 = blockIdx.x * 2;       // head pair (fastest)
    const int b = blockIdx.y;            // batch
    const int slot = blockIdx.z;         // chunk slot
    const int nslot = gridDim.z;
    const int l15 = l & 15, lg = l >> 4;
    const uint4* Wb4 = (const uint4*)Wb;

    f32x4 zero4 = {0.f, 0.f, 0.f, 0.f};
    f32x4 ctx[2][2][2];                  // [hh][rt][vt]
    float sacc[2][2] = {{0.f, 0.f}, {0.f, 0.f}};
#pragma unroll
    for (int hh = 0; hh < 2; ++hh)
#pragma unroll
        for (int a = 0; a < 2; ++a)
#pragma unroll
            for (int c2 = 0; c2 < 2; ++c2) ctx[hh][a][c2] = zero4;

    const float* xw = x + (size_t)b * CIN * n + w * 32 + l15;

    for (int ch = slot; ch < nch; ch += 2 * nslot) {
        const int chB = ch + nslot;
        const bool hasB = chB < nch;

        // ---- load+pack chunk A, then chunk B (independent streams) ----
        s16x8 bxA[2][2], bxB[2][2];
        {
            const float* xp = xw + ch * NP;
#pragma unroll
            for (int pt = 0; pt < 2; ++pt)
#pragma unroll
                for (int kc = 0; kc < 2; ++kc) {
                    float xv[8];
#pragma unroll
                    for (int j = 0; j < 8; ++j)
                        xv[j] = xp[(size_t)(kc * 32 + lg * 8 + j) * n + pt * 16];
                    FragU fu;
#pragma unroll
                    for (int i = 0; i < 4; ++i)
                        fu.u[i] = pack2(xv[2 * i], xv[2 * i + 1]);
                    bxA[pt][kc] = fu.v;
                }
        }
        if (hasB) {
            const float* xp = xw + chB * NP;
#pragma unroll
            for (int pt = 0; pt < 2; ++pt)
#pragma unroll
                for (int kc = 0; kc < 2; ++kc) {
                    float xv[8];
#pragma unroll
                    for (int j = 0; j < 8; ++j)
                        xv[j] = xp[(size_t)(kc * 32 + lg * 8 + j) * n + pt * 16];
                    FragU fu;
#pragma unroll
                    for (int i = 0; i < 4; ++i)
                        fu.u[i] = pack2(xv[2 * i], xv[2 * i + 1]);
                    bxB[pt][kc] = fu.v;
                }
        }

#pragma unroll
        for (int hh = 0; hh < 2; ++hh) {
            const int h = h0 + hh;
            Frag4 ekfA[2][2], vfA[2][2], ekfB[2][2], vfB[2][2];
            // ---- K phase: A and B streams interleaved; only ak live ----
            {
                s16x8 ak[2][2];
#pragma unroll
                for (int rt = 0; rt < 2; ++rt)
#pragma unroll
                    for (int kc = 0; kc < 2; ++kc)
                        ak[rt][kc] = *(const s16x8*)&Wb4[((2 * h + rt) * 2 + kc) * 64 + l];
#pragma unroll
                for (int pt = 0; pt < 2; ++pt)
#pragma unroll
                    for (int rt = 0; rt < 2; ++rt) {
                        f32x4 zA = zero4;
                        zA = __builtin_amdgcn_mfma_f32_16x16x32_bf16(bxA[pt][0], ak[rt][0], zA, 0, 0, 0);
                        zA = __builtin_amdgcn_mfma_f32_16x16x32_bf16(bxA[pt][1], ak[rt][1], zA, 0, 0, 0);
                        f32x4 zB = zero4;
                        if (hasB) {
                            zB = __builtin_amdgcn_mfma_f32_16x16x32_bf16(bxB[pt][0], ak[rt][0], zB, 0, 0, 0);
                            zB = __builtin_amdgcn_mfma_f32_16x16x32_bf16(bxB[pt][1], ak[rt][1], zB, 0, 0, 0);
                        }
                        float a0 = __expf(zA[0]), a1 = __expf(zA[1]);
                        float a2 = __expf(zA[2]), a3 = __expf(zA[3]);
                        sacc[hh][rt] += (a0 + a1) + (a2 + a3);
                        Frag4 fa; fa.u[0] = pack2(a0, a1); fa.u[1] = pack2(a2, a3);
                        ekfA[pt][rt] = fa;
                        if (hasB) {
                            float b0 = __expf(zB[0]), b1 = __expf(zB[1]);
                            float b2 = __expf(zB[2]), b3 = __expf(zB[3]);
                            sacc[hh][rt] += (b0 + b1) + (b2 + b3);
                            Frag4 fb; fb.u[0] = pack2(b0, b1); fb.u[1] = pack2(b2, b3);
                            ekfB[pt][rt] = fb;
                        }
                    }
            }
            __builtin_amdgcn_sched_barrier(0);   // keep av loads out of K phase
            // ---- V phase: A and B streams interleaved; only av live ----
            {
                s16x8 av[2][2];
#pragma unroll
                for (int rt = 0; rt < 2; ++rt)
#pragma unroll
                    for (int kc = 0; kc < 2; ++kc)
                        av[rt][kc] = *(const s16x8*)&Wb4[((8 + 2 * h + rt) * 2 + kc) * 64 + l];
#pragma unroll
                for (int pt = 0; pt < 2; ++pt)
#pragma unroll
                    for (int rt = 0; rt < 2; ++rt) {
                        f32x4 zA = zero4;
                        zA = __builtin_amdgcn_mfma_f32_16x16x32_bf16(bxA[pt][0], av[rt][0], zA, 0, 0, 0);
                        zA = __builtin_amdgcn_mfma_f32_16x16x32_bf16(bxA[pt][1], av[rt][1], zA, 0, 0, 0);
                        Frag4 fa; fa.u[0] = pack2(zA[0], zA[1]); fa.u[1] = pack2(zA[2], zA[3]);
                        vfA[pt][rt] = fa;
                        if (hasB) {
                            f32x4 zB = zero4;
                            zB = __builtin_amdgcn_mfma_f32_16x16x32_bf16(bxB[pt][0], av[rt][0], zB, 0, 0, 0);
                            zB = __builtin_amdgcn_mfma_f32_16x16x32_bf16(bxB[pt][1], av[rt][1], zB, 0, 0, 0);
                            Frag4 fb; fb.u[0] = pack2(zB[0], zB[1]); fb.u[1] = pack2(zB[2], zB[3]);
                            vfB[pt][rt] = fb;
                        }
                    }
            }
            // ---- context: both streams accumulate (MFMA pipelines the acc dep) ----
#pragma unroll
            for (int rt = 0; rt < 2; ++rt)
#pragma unroll
                for (int vt = 0; vt < 2; ++vt) {
                    ctx[hh][rt][vt] = mfma16(ekfA[0][rt].v, vfA[0][vt].v, ctx[hh][rt][vt]);
                    ctx[hh][rt][vt] = mfma16(ekfA[1][rt].v, vfA[1][vt].v, ctx[hh][rt][vt]);
                    if (hasB) {
                        ctx[hh][rt][vt] = mfma16(ekfB[0][rt].v, vfB[0][vt].v, ctx[hh][rt][vt]);
                        ctx[hh][rt][vt] = mfma16(ekfB[1][rt].v, vfB[1][vt].v, ctx[hh][rt][vt]);
                    }
                }
        }
    }

    // ---- cross-wave reduce, write both heads' partials ----
    float* Xf = RED;
    float* Sf = RED + 4096;
    float* Pb = P + (size_t)(b * nslot + slot) * 4224;
#pragma unroll
    for (int hh = 0; hh < 2; ++hh) {
        const int h = h0 + hh;
        __syncthreads();   // hh=0: trivial; hh=1: all waves done reading Xf
#pragma unroll
        for (int rt = 0; rt < 2; ++rt)
#pragma unroll
            for (int vt = 0; vt < 2; ++vt)
#pragma unroll
                for (int r = 0; r < 4; ++r) {
                    int d = rt * 16 + lg * 4 + r, e = vt * 16 + l15;
                    Xf[w * 1024 + d * 32 + e] = ctx[hh][rt][vt][r];
                }
#pragma unroll
        for (int rt = 0; rt < 2; ++rt) {
            float s = sacc[hh][rt];
            s += __shfl_xor(s, 16);
            s += __shfl_xor(s, 32);
            if (l < 16) Sf[w * 32 + rt * 16 + l15] = s;
        }
        __syncthreads();
        for (int i = tid; i < 1024; i += 256)
            Pb[h * 1056 + i] = Xf[i] + Xf[1024 + i] + Xf[2048 + i] + Xf[3072 + i];
        if (tid < 32)
            Pb[h * 1056 + 1024 + tid] = Sf[tid] + Sf[32 + tid] + Sf[64 + tid] + Sf[96 + tid];
    }
}

// K2: slot-sliced partial reduce: P[b][slot][4224] -> P2[b][16][4224]
__global__ __launch_bounds__(256) void reduce_p1(
    const float* __restrict__ P, float* __restrict__ P2, int nblk)
{
    const int idx = blockIdx.x * 256 + threadIdx.x;
    if (idx >= 4224) return;
    const int b = blockIdx.z, sz = blockIdx.y;
    float acc = 0.f;
    for (int slot = sz; slot < nblk; slot += 16)
        acc += P[((size_t)(b * nblk + slot)) * 4224 + idx];
    P2[((size_t)(b * 16 + sz)) * 4224 + idx] = acc;
}

// K3: final 16-slot reduce (merged) + build Mt[c][o]; (o-slice=8, batch) blocks.
__global__ __launch_bounds__(256) void build_M(
    const float* __restrict__ P2, const float* __restrict__ Wout,
    const float* __restrict__ Wqkv, float* __restrict__ Mt)
{
    __shared__ float Rsh[4224];
    __shared__ float ctx[4096];          // [h][e][d] (transposed)
    __shared__ float Ash[8 * 128];       // A[oo][h*32+d]
    const int b = blockIdx.y;
    const int o0 = blockIdx.x * 8;
    const int tid = threadIdx.x;
    for (int i = tid; i < 4224; i += 256) {
        float acc = 0.f;
#pragma unroll
        for (int s = 0; s < 16; ++s)
            acc += P2[((size_t)(b * 16 + s)) * 4224 + i];
        Rsh[i] = acc;
    }
    __syncthreads();
    for (int i = tid; i < 4096; i += 256) {
        const int hh = i >> 10, rr = i & 1023, e = rr >> 5, d = rr & 31;
        ctx[i] = Rsh[hh * 1056 + d * 32 + e] / Rsh[hh * 1056 + 1024 + d];
    }
    __syncthreads();
    for (int i = tid; i < 1024; i += 256) {
        const int oo = i >> 7, m = i & 127, hh = m >> 5, d = m & 31;
        float acc = 0.f;
#pragma unroll
        for (int e = 0; e < 32; ++e)
            acc += Wout[(o0 + oo) * 128 + hh * 32 + e] * ctx[hh * 1024 + e * 32 + d];
        Ash[i] = acc;
    }
    __syncthreads();
    const float scale = 0.17677669529663687f;
    for (int i = tid; i < 512; i += 256) {
        const int oo = i >> 6, c = i & 63;
        float acc = 0.f;
#pragma unroll
        for (int m = 0; m < 128; ++m)
            acc += Ash[oo * 128 + m] * Wqkv[m * 64 + c];
        Mt[b * 4096 + c * 64 + (o0 + oo)] = acc * scale;   // transposed store
    }
}

// K4: y[b,o,p] = sum_c Mt[c][o] x[b,c,p] + b_out[o]
__global__ __launch_bounds__(256, 4) void final_proj(
    const float* __restrict__ x, const float* __restrict__ Mt,
    const float* __restrict__ bout, float* __restrict__ y, int n)
{
    const int b = blockIdx.y;
    const int p = blockIdx.x * 256 + threadIdx.x;
    const float* xb = x + (size_t)b * CIN * n + p;
    const float* M = Mt + b * 4096;
    float acc[64];
#pragma unroll
    for (int o = 0; o < 64; ++o) acc[o] = bout[o];
    for (int c = 0; c < 64; ++c) {
        const float xv = xb[(size_t)c * n];
        const float* Mr = M + c * 64;
#pragma unroll
        for (int o = 0; o < 64; ++o) acc[o] += Mr[o] * xv;
    }
    float* yb = y + (size_t)b * CIN * n + p;
#pragma unroll
    for (int o = 0; o < 64; ++o) yb[(size_t)o * n] = acc[o];
}

extern "C" void kernel_launch(void* const* d_in, const int* in_sizes, int n_in,
                              void* d_out, int out_size, void* d_ws, size_t ws_size,
                              hipStream_t stream) {
    const float* x    = (const float*)d_in[0];
    const float* Wqkv = (const float*)d_in[1];
    const float* Wout = (const float*)d_in[2];
    const float* bout = (const float*)d_in[3];
    float* y = (float*)d_out;

    const int n = in_sizes[0] / 128;   // 110592
    const int nch = n / NP;            // 864

    // ws-adaptive partial-slot count (216 -> 2 chunk-PAIRS/block)
    int BLKX = 216;
    for (;;) {
        size_t need = 32768 + (size_t)2 * BLKX * 4224 * 4   // P
                    + (size_t)2 * 16 * 4224 * 4             // P2
                    + 2 * 4096 * 4;                         // Mt
        if (need <= ws_size || BLKX <= 64) break;
        BLKX >>= 1;
    }
    unsigned short* Wb = (unsigned short*)d_ws;                  // 32 KiB
    float* P  = (float*)((char*)d_ws + 32768);
    float* P2 = P + (size_t)2 * BLKX * 4224;
    float* Mt = P2 + (size_t)2 * 16 * 4224;

    prep_w<<<8, 256, 0, stream>>>(Wqkv, Wb);
    lin_attn_ctx<<<dim3(2, 2, BLKX), 256, 0, stream>>>(x, Wb, P, n, nch);
    reduce_p1<<<dim3(17, 16, 2), 256, 0, stream>>>(P, P2, BLKX);
    build_M<<<dim3(8, 2), 256, 0, stream>>>(P2, Wout, Wqkv, Mt);
    final_proj<<<dim3(n / 256, 2), 256, 0, stream>>>(x, Mt, bout, y, n);
}

// Round 25
// 84.266 us; speedup vs baseline: 1.2460x; 1.0293x over previous
//
#include <hip/hip_runtime.h>
#include <math.h>

#define CIN 64
#define NP 128

typedef float f32x4 __attribute__((ext_vector_type(4)));
typedef float f32x2 __attribute__((ext_vector_type(2)));
typedef short s16x8 __attribute__((ext_vector_type(8)));
typedef short s16x4 __attribute__((ext_vector_type(4)));

union FragU { s16x8 v; unsigned u[4]; };
union Frag4 { s16x4 v; unsigned u[2]; };

static __device__ __forceinline__ unsigned short f2b(float f) {
    unsigned u = __builtin_bit_cast(unsigned, f);
    unsigned r = (u + 0x7FFFu + ((u >> 16) & 1u)) >> 16;   // RNE (proven R1/R2/R5/R8)
    return (unsigned short)r;
}
// pack two f32 -> bf16x2 word, software RNE — NOT v_cvt_pk (R6: raw instr != RNE)
static __device__ __forceinline__ unsigned pack2(float lo, float hi) {
    return (unsigned)f2b(lo) | ((unsigned)f2b(hi) << 16);
}

// 16x16x16 bf16 MFMA (gfx950 instruction per ISA §10; proven R14-R23)
static __device__ __forceinline__ f32x4 mfma16(s16x4 a, s16x4 b, f32x4 c) {
#if __has_builtin(__builtin_amdgcn_mfma_f32_16x16x16bf16_1k)
    return __builtin_amdgcn_mfma_f32_16x16x16bf16_1k(a, b, c, 0, 0, 0);
#else
    asm volatile("v_mfma_f32_16x16x16_bf16 %0, %1, %2, %0\n\ts_nop 7\n\ts_nop 7"
                 : "+v"(c) : "v"(a), "v"(b));
    return c;
#endif
}

// K1: fused W-prep + kv-projection + exp + context, all in registers; TWO
// heads/block, K/V phase-split, __launch_bounds__(256,2) — the R18 structure.
// R25 fix: the fused-prep fill loop covers 1024 entries (R24 bug: bound was
// 512, leaving head-1's fragments uninitialized -> NaN). Table = 2 heads x
// {K,V} x 2rt x 2kc x 64 lanes = 1024 x 16B = 16KB, aliased onto RED
// (16.9KB; epilogue's first __syncthreads precedes the Xf overwrite).
__global__ __launch_bounds__(256, 2) void lin_attn_ctx(
    const float* __restrict__ x, const float* __restrict__ Wqkv,
    float* __restrict__ P, int n, int nch)
{
    __shared__ __align__(16) float RED[4224];   // WL (16KB) during loop; Xf/Sf in epilogue

    const int tid = threadIdx.x;
    const int l = tid & 63;
    const int w = tid >> 6;
    const int h0 = blockIdx.x * 2;       // head pair (fastest)
    const int b = blockIdx.y;            // batch
    const int slot = blockIdx.z;         // chunk slot
    const int nslot = gridDim.z;
    const int l15 = l & 15, lg = l >> 4;

    // ---- fused prep_w: 1024 x 16B fragment entries -> LDS ----
    // entry e: lane=e&63, kc=(e>>6)&1, rt=(e>>7)&1, kv=(e>>8)&1, hh=e>>9
    {
        uint4* WL4 = (uint4*)RED;
        for (int e = tid; e < 1024; e += 256) {
            const int lane = e & 63, kc = (e >> 6) & 1, rt = (e >> 7) & 1;
            const int kv = (e >> 8) & 1, hh = e >> 9;
            const int row = 128 + kv * 128 + (2 * (h0 + hh) + rt) * 16 + (lane & 15);
            const float* src = Wqkv + row * 64 + kc * 32 + (lane >> 4) * 8;
            uint4 q;
            q.x = pack2(src[0], src[1]);
            q.y = pack2(src[2], src[3]);
            q.z = pack2(src[4], src[5]);
            q.w = pack2(src[6], src[7]);
            WL4[e] = q;
        }
        __syncthreads();
    }
    const s16x8* WLf = (const s16x8*)RED;

    f32x4 zero4 = {0.f, 0.f, 0.f, 0.f};
    f32x4 ctx[2][2][2];                  // [hh][rt][vt]
    float sacc[2][2] = {{0.f, 0.f}, {0.f, 0.f}};
#pragma unroll
    for (int hh = 0; hh < 2; ++hh)
#pragma unroll
        for (int a = 0; a < 2; ++a)
#pragma unroll
            for (int c2 = 0; c2 < 2; ++c2) ctx[hh][a][c2] = zero4;

    const float* xw = x + (size_t)b * CIN * n + w * 32 + l15;

    for (int ch = slot; ch < nch; ch += nslot) {
        // ---- direct global -> X-fragment loads, pack immediately ----
        const float* xp = xw + ch * NP;
        s16x8 bx[2][2];
#pragma unroll
        for (int pt = 0; pt < 2; ++pt)
#pragma unroll
            for (int kc = 0; kc < 2; ++kc) {
                float xv[8];
#pragma unroll
                for (int j = 0; j < 8; ++j)
                    xv[j] = xp[(size_t)(kc * 32 + lg * 8 + j) * n + pt * 16];
                FragU fu;
#pragma unroll
                for (int i = 0; i < 4; ++i)
                    fu.u[i] = pack2(xv[2 * i], xv[2 * i + 1]);
                bx[pt][kc] = fu.v;
            }

#pragma unroll
        for (int hh = 0; hh < 2; ++hh) {
            Frag4 ekf[2][2], vf[2][2];       // [pt][rt]
            // ---- K phase: only ak fragments live ----
            {
                s16x8 ak[2][2];
#pragma unroll
                for (int rt = 0; rt < 2; ++rt)
#pragma unroll
                    for (int kc = 0; kc < 2; ++kc)
                        ak[rt][kc] = WLf[(((hh * 2 + 0) * 2 + rt) * 2 + kc) * 64 + l];
#pragma unroll
                for (int pt = 0; pt < 2; ++pt)
#pragma unroll
                    for (int rt = 0; rt < 2; ++rt) {
                        f32x4 z = zero4;
                        z = __builtin_amdgcn_mfma_f32_16x16x32_bf16(bx[pt][0], ak[rt][0], z, 0, 0, 0);
                        z = __builtin_amdgcn_mfma_f32_16x16x32_bf16(bx[pt][1], ak[rt][1], z, 0, 0, 0);
                        float e0 = __expf(z[0]), e1 = __expf(z[1]);
                        float e2 = __expf(z[2]), e3 = __expf(z[3]);
                        sacc[hh][rt] += (e0 + e1) + (e2 + e3);
                        Frag4 fe; fe.u[0] = pack2(e0, e1); fe.u[1] = pack2(e2, e3);
                        ekf[pt][rt] = fe;
                    }
            }
            __builtin_amdgcn_sched_barrier(0);   // keep av loads out of K phase
            // ---- V phase: only av fragments live ----
            {
                s16x8 av[2][2];
#pragma unroll
                for (int rt = 0; rt < 2; ++rt)
#pragma unroll
                    for (int kc = 0; kc < 2; ++kc)
                        av[rt][kc] = WLf[(((hh * 2 + 1) * 2 + rt) * 2 + kc) * 64 + l];
#pragma unroll
                for (int pt = 0; pt < 2; ++pt)
#pragma unroll
                    for (int rt = 0; rt < 2; ++rt) {
                        f32x4 z2 = zero4;
                        z2 = __builtin_amdgcn_mfma_f32_16x16x32_bf16(bx[pt][0], av[rt][0], z2, 0, 0, 0);
                        z2 = __builtin_amdgcn_mfma_f32_16x16x32_bf16(bx[pt][1], av[rt][1], z2, 0, 0, 0);
                        Frag4 fv; fv.u[0] = pack2(z2[0], z2[1]); fv.u[1] = pack2(z2[2], z2[3]);
                        vf[pt][rt] = fv;
                    }
            }
            // ---- context: ctx[hh][rt][vt] += EK x V^T, K=pos ----
#pragma unroll
            for (int rt = 0; rt < 2; ++rt)
#pragma unroll
                for (int vt = 0; vt < 2; ++vt) {
                    ctx[hh][rt][vt] = mfma16(ekf[0][rt].v, vf[0][vt].v, ctx[hh][rt][vt]);
                    ctx[hh][rt][vt] = mfma16(ekf[1][rt].v, vf[1][vt].v, ctx[hh][rt][vt]);
                }
        }
    }

    // ---- cross-wave reduce, write both heads' partials ----
    float* Xf = RED;
    float* Sf = RED + 4096;
    float* Pb = P + (size_t)(b * nslot + slot) * 4224;
#pragma unroll
    for (int hh = 0; hh < 2; ++hh) {
        const int h = h0 + hh;
        __syncthreads();   // hh=0: all waves exited main loop (WL now dead); hh=1: Xf consumed
#pragma unroll
        for (int rt = 0; rt < 2; ++rt)
#pragma unroll
            for (int vt = 0; vt < 2; ++vt)
#pragma unroll
                for (int r = 0; r < 4; ++r) {
                    int d = rt * 16 + lg * 4 + r, e = vt * 16 + l15;
                    Xf[w * 1024 + d * 32 + e] = ctx[hh][rt][vt][r];
                }
#pragma unroll
        for (int rt = 0; rt < 2; ++rt) {
            float s = sacc[hh][rt];
            s += __shfl_xor(s, 16);
            s += __shfl_xor(s, 32);
            if (l < 16) Sf[w * 32 + rt * 16 + l15] = s;
        }
        __syncthreads();
        for (int i = tid; i < 1024; i += 256)
            Pb[h * 1056 + i] = Xf[i] + Xf[1024 + i] + Xf[2048 + i] + Xf[3072 + i];
        if (tid < 32)
            Pb[h * 1056 + 1024 + tid] = Sf[tid] + Sf[32 + tid] + Sf[64 + tid] + Sf[96 + tid];
    }
}

// K2: slot-sliced partial reduce: P[b][slot][4224] -> P2[b][16][4224]
__global__ __launch_bounds__(256) void reduce_p1(
    const float* __restrict__ P, float* __restrict__ P2, int nblk)
{
    const int idx = blockIdx.x * 256 + threadIdx.x;
    if (idx >= 4224) return;
    const int b = blockIdx.z, sz = blockIdx.y;
    float acc = 0.f;
    for (int slot = sz; slot < nblk; slot += 16)
        acc += P[((size_t)(b * nblk + slot)) * 4224 + idx];
    P2[((size_t)(b * 16 + sz)) * 4224 + idx] = acc;
}

// K3: final 16-slot reduce (merged) + build Mt[c][o]; (o-slice=8, batch) blocks.
__global__ __launch_bounds__(256) void build_M(
    const float* __restrict__ P2, const float* __restrict__ Wout,
    const float* __restrict__ Wqkv, float* __restrict__ Mt)
{
    __shared__ float Rsh[4224];
    __shared__ float ctx[4096];          // [h][e][d] (transposed)
    __shared__ float Ash[8 * 128];       // A[oo][h*32+d]
    const int b = blockIdx.y;
    const int o0 = blockIdx.x * 8;
    const int tid = threadIdx.x;
    for (int i = tid; i < 4224; i += 256) {
        float acc = 0.f;
#pragma unroll
        for (int s = 0; s < 16; ++s)
            acc += P2[((size_t)(b * 16 + s)) * 4224 + i];
        Rsh[i] = acc;
    }
    __syncthreads();
    for (int i = tid; i < 4096; i += 256) {
        const int hh = i >> 10, rr = i & 1023, e = rr >> 5, d = rr & 31;
        ctx[i] = Rsh[hh * 1056 + d * 32 + e] / Rsh[hh * 1056 + 1024 + d];
    }
    __syncthreads();
    for (int i = tid; i < 1024; i += 256) {
        const int oo = i >> 7, m = i & 127, hh = m >> 5, d = m & 31;
        float acc = 0.f;
#pragma unroll
        for (int e = 0; e < 32; ++e)
            acc += Wout[(o0 + oo) * 128 + hh * 32 + e] * ctx[hh * 1024 + e * 32 + d];
        Ash[i] = acc;
    }
    __syncthreads();
    const float scale = 0.17677669529663687f;
    for (int i = tid; i < 512; i += 256) {
        const int oo = i >> 6, c = i & 63;
        float acc = 0.f;
#pragma unroll
        for (int m = 0; m < 128; ++m)
            acc += Ash[oo * 128 + m] * Wqkv[m * 64 + c];
        Mt[b * 4096 + c * 64 + (o0 + oo)] = acc * scale;   // transposed store
    }
}

// K4: y[b,o,p] = sum_c Mt[c][o] x[b,c,p] + b_out[o] — packed-f32 (v_pk_fma)
__global__ __launch_bounds__(256, 4) void final_proj(
    const float* __restrict__ x, const float* __restrict__ Mt,
    const float* __restrict__ bout, float* __restrict__ y, int n)
{
    const int b = blockIdx.y;
    const int p = blockIdx.x * 256 + threadIdx.x;
    const float* xb = x + (size_t)b * CIN * n + p;
    const float* M = Mt + b * 4096;
    f32x2 acc[32];
#pragma unroll
    for (int o = 0; o < 32; ++o) {
        f32x2 t = { bout[2 * o], bout[2 * o + 1] };
        acc[o] = t;
    }
    for (int c = 0; c < 64; ++c) {
        const float xv = xb[(size_t)c * n];
        f32x2 xv2 = { xv, xv };
        const f32x2* Mr = (const f32x2*)(M + c * 64);
#pragma unroll
        for (int o = 0; o < 32; ++o)
            acc[o] += Mr[o] * xv2;
    }
    float* yb = y + (size_t)b * CIN * n + p;
#pragma unroll
    for (int o = 0; o < 32; ++o) {
        yb[(size_t)(2 * o) * n]     = acc[o][0];
        yb[(size_t)(2 * o + 1) * n] = acc[o][1];
    }
}

extern "C" void kernel_launch(void* const* d_in, const int* in_sizes, int n_in,
                              void* d_out, int out_size, void* d_ws, size_t ws_size,
                              hipStream_t stream) {
    const float* x    = (const float*)d_in[0];
    const float* Wqkv = (const float*)d_in[1];
    const float* Wout = (const float*)d_in[2];
    const float* bout = (const float*)d_in[3];
    float* y = (float*)d_out;

    const int n = in_sizes[0] / 128;   // 110592
    const int nch = n / NP;            // 864

    // ws-adaptive partial-slot count (216 -> 4 chunks/block)
    int BLKX = 216;
    for (;;) {
        size_t need = (size_t)2 * BLKX * 4224 * 4            // P
                    + (size_t)2 * 16 * 4224 * 4              // P2
                    + 2 * 4096 * 4;                          // Mt
        if (need <= ws_size || BLKX <= 64) break;
        BLKX >>= 1;
    }
    float* P  = (float*)d_ws;
    float* P2 = P + (size_t)2 * BLKX * 4224;
    float* Mt = P2 + (size_t)2 * 16 * 4224;

    lin_attn_ctx<<<dim3(2, 2, BLKX), 256, 0, stream>>>(x, Wqkv, P, n, nch);
    reduce_p1<<<dim3(17, 16, 2), 256, 0, stream>>>(P, P2, BLKX);
    build_M<<<dim3(8, 2), 256, 0, stream>>>(P2, Wout, Wqkv, Mt);
    final_proj<<<dim3(n / 256, 2), 256, 0, stream>>>(x, Mt, bout, y, n);
}

// Round 26
// 82.743 us; speedup vs baseline: 1.2689x; 1.0184x over previous
//
#include <hip/hip_runtime.h>
#include <math.h>

#define CIN 64
#define NP 128

typedef float f32x4 __attribute__((ext_vector_type(4)));
typedef float f32x2 __attribute__((ext_vector_type(2)));
typedef short s16x8 __attribute__((ext_vector_type(8)));
typedef short s16x4 __attribute__((ext_vector_type(4)));

union FragU { s16x8 v; unsigned u[4]; };
union Frag4 { s16x4 v; unsigned u[2]; };

static __device__ __forceinline__ unsigned short f2b(float f) {
    unsigned u = __builtin_bit_cast(unsigned, f);
    unsigned r = (u + 0x7FFFu + ((u >> 16) & 1u)) >> 16;   // RNE (proven R1/R2/R5/R8)
    return (unsigned short)r;
}
// pack two f32 -> bf16x2 word, software RNE — NOT v_cvt_pk (R6: raw instr != RNE)
static __device__ __forceinline__ unsigned pack2(float lo, float hi) {
    return (unsigned)f2b(lo) | ((unsigned)f2b(hi) << 16);
}

// 16x16x16 bf16 MFMA (gfx950 instruction per ISA §10; proven R14-R25)
static __device__ __forceinline__ f32x4 mfma16(s16x4 a, s16x4 b, f32x4 c) {
#if __has_builtin(__builtin_amdgcn_mfma_f32_16x16x16bf16_1k)
    return __builtin_amdgcn_mfma_f32_16x16x16bf16_1k(a, b, c, 0, 0, 0);
#else
    asm volatile("v_mfma_f32_16x16x16_bf16 %0, %1, %2, %0\n\ts_nop 7\n\ts_nop 7"
                 : "+v"(c) : "v"(a), "v"(b));
    return c;
#endif
}

// K1: fused W-prep + kv-projection + exp + context, all in registers; TWO
// heads/block, K/V phase-split, W in LDS (R25: VGPR dropped to 80).
// R26 change: __launch_bounds__(256,4) — 80 VGPR + 32 AGPR = 112 unified regs
// fits the 128/wave cap -> 4 blocks/CU = 4 waves/SIMD (2x the R18-R25
// occupancy that kept the latency-bound kernel at ~40us). 864 blocks all
// co-resident (<= 1024 slots), uniform 4 chunks each, zero tail.
__global__ __launch_bounds__(256, 4) void lin_attn_ctx(
    const float* __restrict__ x, const float* __restrict__ Wqkv,
    float* __restrict__ P, int n, int nch)
{
    __shared__ __align__(16) float RED[4224];   // WL (16KB) during loop; Xf/Sf in epilogue

    const int tid = threadIdx.x;
    const int l = tid & 63;
    const int w = tid >> 6;
    const int h0 = blockIdx.x * 2;       // head pair (fastest)
    const int b = blockIdx.y;            // batch
    const int slot = blockIdx.z;         // chunk slot
    const int nslot = gridDim.z;
    const int l15 = l & 15, lg = l >> 4;

    // ---- fused prep_w: 1024 x 16B fragment entries -> LDS ----
    // entry e: lane=e&63, kc=(e>>6)&1, rt=(e>>7)&1, kv=(e>>8)&1, hh=e>>9
    {
        uint4* WL4 = (uint4*)RED;
        for (int e = tid; e < 1024; e += 256) {
            const int lane = e & 63, kc = (e >> 6) & 1, rt = (e >> 7) & 1;
            const int kv = (e >> 8) & 1, hh = e >> 9;
            const int row = 128 + kv * 128 + (2 * (h0 + hh) + rt) * 16 + (lane & 15);
            const float* src = Wqkv + row * 64 + kc * 32 + (lane >> 4) * 8;
            uint4 q;
            q.x = pack2(src[0], src[1]);
            q.y = pack2(src[2], src[3]);
            q.z = pack2(src[4], src[5]);
            q.w = pack2(src[6], src[7]);
            WL4[e] = q;
        }
        __syncthreads();
    }
    const s16x8* WLf = (const s16x8*)RED;

    f32x4 zero4 = {0.f, 0.f, 0.f, 0.f};
    f32x4 ctx[2][2][2];                  // [hh][rt][vt]
    float sacc[2][2] = {{0.f, 0.f}, {0.f, 0.f}};
#pragma unroll
    for (int hh = 0; hh < 2; ++hh)
#pragma unroll
        for (int a = 0; a < 2; ++a)
#pragma unroll
            for (int c2 = 0; c2 < 2; ++c2) ctx[hh][a][c2] = zero4;

    const float* xw = x + (size_t)b * CIN * n + w * 32 + l15;

    for (int ch = slot; ch < nch; ch += nslot) {
        // ---- direct global -> X-fragment loads, pack immediately ----
        const float* xp = xw + ch * NP;
        s16x8 bx[2][2];
#pragma unroll
        for (int pt = 0; pt < 2; ++pt)
#pragma unroll
            for (int kc = 0; kc < 2; ++kc) {
                float xv[8];
#pragma unroll
                for (int j = 0; j < 8; ++j)
                    xv[j] = xp[(size_t)(kc * 32 + lg * 8 + j) * n + pt * 16];
                FragU fu;
#pragma unroll
                for (int i = 0; i < 4; ++i)
                    fu.u[i] = pack2(xv[2 * i], xv[2 * i + 1]);
                bx[pt][kc] = fu.v;
            }

#pragma unroll
        for (int hh = 0; hh < 2; ++hh) {
            Frag4 ekf[2][2], vf[2][2];       // [pt][rt]
            // ---- K phase: only ak fragments live ----
            {
                s16x8 ak[2][2];
#pragma unroll
                for (int rt = 0; rt < 2; ++rt)
#pragma unroll
                    for (int kc = 0; kc < 2; ++kc)
                        ak[rt][kc] = WLf[(((hh * 2 + 0) * 2 + rt) * 2 + kc) * 64 + l];
#pragma unroll
                for (int pt = 0; pt < 2; ++pt)
#pragma unroll
                    for (int rt = 0; rt < 2; ++rt) {
                        f32x4 z = zero4;
                        z = __builtin_amdgcn_mfma_f32_16x16x32_bf16(bx[pt][0], ak[rt][0], z, 0, 0, 0);
                        z = __builtin_amdgcn_mfma_f32_16x16x32_bf16(bx[pt][1], ak[rt][1], z, 0, 0, 0);
                        float e0 = __expf(z[0]), e1 = __expf(z[1]);
                        float e2 = __expf(z[2]), e3 = __expf(z[3]);
                        sacc[hh][rt] += (e0 + e1) + (e2 + e3);
                        Frag4 fe; fe.u[0] = pack2(e0, e1); fe.u[1] = pack2(e2, e3);
                        ekf[pt][rt] = fe;
                    }
            }
            __builtin_amdgcn_sched_barrier(0);   // keep av loads out of K phase
            // ---- V phase: only av fragments live ----
            {
                s16x8 av[2][2];
#pragma unroll
                for (int rt = 0; rt < 2; ++rt)
#pragma unroll
                    for (int kc = 0; kc < 2; ++kc)
                        av[rt][kc] = WLf[(((hh * 2 + 1) * 2 + rt) * 2 + kc) * 64 + l];
#pragma unroll
                for (int pt = 0; pt < 2; ++pt)
#pragma unroll
                    for (int rt = 0; rt < 2; ++rt) {
                        f32x4 z2 = zero4;
                        z2 = __builtin_amdgcn_mfma_f32_16x16x32_bf16(bx[pt][0], av[rt][0], z2, 0, 0, 0);
                        z2 = __builtin_amdgcn_mfma_f32_16x16x32_bf16(bx[pt][1], av[rt][1], z2, 0, 0, 0);
                        Frag4 fv; fv.u[0] = pack2(z2[0], z2[1]); fv.u[1] = pack2(z2[2], z2[3]);
                        vf[pt][rt] = fv;
                    }
            }
            // ---- context: ctx[hh][rt][vt] += EK x V^T, K=pos ----
#pragma unroll
            for (int rt = 0; rt < 2; ++rt)
#pragma unroll
                for (int vt = 0; vt < 2; ++vt) {
                    ctx[hh][rt][vt] = mfma16(ekf[0][rt].v, vf[0][vt].v, ctx[hh][rt][vt]);
                    ctx[hh][rt][vt] = mfma16(ekf[1][rt].v, vf[1][vt].v, ctx[hh][rt][vt]);
                }
        }
    }

    // ---- cross-wave reduce, write both heads' partials ----
    float* Xf = RED;
    float* Sf = RED + 4096;
    float* Pb = P + (size_t)(b * nslot + slot) * 4224;
#pragma unroll
    for (int hh = 0; hh < 2; ++hh) {
        const int h = h0 + hh;
        __syncthreads();   // hh=0: all waves exited main loop (WL now dead); hh=1: Xf consumed
#pragma unroll
        for (int rt = 0; rt < 2; ++rt)
#pragma unroll
            for (int vt = 0; vt < 2; ++vt)
#pragma unroll
                for (int r = 0; r < 4; ++r) {
                    int d = rt * 16 + lg * 4 + r, e = vt * 16 + l15;
                    Xf[w * 1024 + d * 32 + e] = ctx[hh][rt][vt][r];
                }
#pragma unroll
        for (int rt = 0; rt < 2; ++rt) {
            float s = sacc[hh][rt];
            s += __shfl_xor(s, 16);
            s += __shfl_xor(s, 32);
            if (l < 16) Sf[w * 32 + rt * 16 + l15] = s;
        }
        __syncthreads();
        for (int i = tid; i < 1024; i += 256)
            Pb[h * 1056 + i] = Xf[i] + Xf[1024 + i] + Xf[2048 + i] + Xf[3072 + i];
        if (tid < 32)
            Pb[h * 1056 + 1024 + tid] = Sf[tid] + Sf[32 + tid] + Sf[64 + tid] + Sf[96 + tid];
    }
}

// K2: slot-sliced partial reduce: P[b][slot][4224] -> P2[b][16][4224]
__global__ __launch_bounds__(256) void reduce_p1(
    const float* __restrict__ P, float* __restrict__ P2, int nblk)
{
    const int idx = blockIdx.x * 256 + threadIdx.x;
    if (idx >= 4224) return;
    const int b = blockIdx.z, sz = blockIdx.y;
    float acc = 0.f;
    for (int slot = sz; slot < nblk; slot += 16)
        acc += P[((size_t)(b * nblk + slot)) * 4224 + idx];
    P2[((size_t)(b * 16 + sz)) * 4224 + idx] = acc;
}

// K3: final 16-slot reduce (merged) + build Mt[c][o]; (o-slice=8, batch) blocks.
__global__ __launch_bounds__(256) void build_M(
    const float* __restrict__ P2, const float* __restrict__ Wout,
    const float* __restrict__ Wqkv, float* __restrict__ Mt)
{
    __shared__ float Rsh[4224];
    __shared__ float ctx[4096];          // [h][e][d] (transposed)
    __shared__ float Ash[8 * 128];       // A[oo][h*32+d]
    const int b = blockIdx.y;
    const int o0 = blockIdx.x * 8;
    const int tid = threadIdx.x;
    for (int i = tid; i < 4224; i += 256) {
        float acc = 0.f;
#pragma unroll
        for (int s = 0; s < 16; ++s)
            acc += P2[((size_t)(b * 16 + s)) * 4224 + i];
        Rsh[i] = acc;
    }
    __syncthreads();
    for (int i = tid; i < 4096; i += 256) {
        const int hh = i >> 10, rr = i & 1023, e = rr >> 5, d = rr & 31;
        ctx[i] = Rsh[hh * 1056 + d * 32 + e] / Rsh[hh * 1056 + 1024 + d];
    }
    __syncthreads();
    for (int i = tid; i < 1024; i += 256) {
        const int oo = i >> 7, m = i & 127, hh = m >> 5, d = m & 31;
        float acc = 0.f;
#pragma unroll
        for (int e = 0; e < 32; ++e)
            acc += Wout[(o0 + oo) * 128 + hh * 32 + e] * ctx[hh * 1024 + e * 32 + d];
        Ash[i] = acc;
    }
    __syncthreads();
    const float scale = 0.17677669529663687f;
    for (int i = tid; i < 512; i += 256) {
        const int oo = i >> 6, c = i & 63;
        float acc = 0.f;
#pragma unroll
        for (int m = 0; m < 128; ++m)
            acc += Ash[oo * 128 + m] * Wqkv[m * 64 + c];
        Mt[b * 4096 + c * 64 + (o0 + oo)] = acc * scale;   // transposed store
    }
}

// K4: y[b,o,p] = sum_c Mt[c][o] x[b,c,p] + b_out[o] — packed-f32 (v_pk_fma)
__global__ __launch_bounds__(256, 4) void final_proj(
    const float* __restrict__ x, const float* __restrict__ Mt,
    const float* __restrict__ bout, float* __restrict__ y, int n)
{
    const int b = blockIdx.y;
    const int p = blockIdx.x * 256 + threadIdx.x;
    const float* xb = x + (size_t)b * CIN * n + p;
    const float* M = Mt + b * 4096;
    f32x2 acc[32];
#pragma unroll
    for (int o = 0; o < 32; ++o) {
        f32x2 t = { bout[2 * o], bout[2 * o + 1] };
        acc[o] = t;
    }
    for (int c = 0; c < 64; ++c) {
        const float xv = xb[(size_t)c * n];
        f32x2 xv2 = { xv, xv };
        const f32x2* Mr = (const f32x2*)(M + c * 64);
#pragma unroll
        for (int o = 0; o < 32; ++o)
            acc[o] += Mr[o] * xv2;
    }
    float* yb = y + (size_t)b * CIN * n + p;
#pragma unroll
    for (int o = 0; o < 32; ++o) {
        yb[(size_t)(2 * o) * n]     = acc[o][0];
        yb[(size_t)(2 * o + 1) * n] = acc[o][1];
    }
}

extern "C" void kernel_launch(void* const* d_in, const int* in_sizes, int n_in,
                              void* d_out, int out_size, void* d_ws, size_t ws_size,
                              hipStream_t stream) {
    const float* x    = (const float*)d_in[0];
    const float* Wqkv = (const float*)d_in[1];
    const float* Wout = (const float*)d_in[2];
    const float* bout = (const float*)d_in[3];
    float* y = (float*)d_out;

    const int n = in_sizes[0] / 128;   // 110592
    const int nch = n / NP;            // 864

    // ws-adaptive partial-slot count (216 -> 4 chunks/block)
    int BLKX = 216;
    for (;;) {
        size_t need = (size_t)2 * BLKX * 4224 * 4            // P
                    + (size_t)2 * 16 * 4224 * 4              // P2
                    + 2 * 4096 * 4;                          // Mt
        if (need <= ws_size || BLKX <= 64) break;
        BLKX >>= 1;
    }
    float* P  = (float*)d_ws;
    float* P2 = P + (size_t)2 * BLKX * 4224;
    float* Mt = P2 + (size_t)2 * 16 * 4224;

    lin_attn_ctx<<<dim3(2, 2, BLKX), 256, 0, stream>>>(x, Wqkv, P, n, nch);
    reduce_p1<<<dim3(17, 16, 2), 256, 0, stream>>>(P, P2, BLKX);
    build_M<<<dim3(8, 2), 256, 0, stream>>>(P2, Wout, Wqkv, Mt);
    final_proj<<<dim3(n / 256, 2), 256, 0, stream>>>(x, Mt, bout, y, n);
}

// Round 27
// 82.386 us; speedup vs baseline: 1.2744x; 1.0043x over previous
//
#include <hip/hip_runtime.h>
#include <math.h>

#define CIN 64
#define NP 128

typedef float f32x4 __attribute__((ext_vector_type(4)));
typedef float f32x2 __attribute__((ext_vector_type(2)));
typedef short s16x8 __attribute__((ext_vector_type(8)));
typedef short s16x4 __attribute__((ext_vector_type(4)));

union FragU { s16x8 v; unsigned u[4]; };
union Frag4 { s16x4 v; unsigned u[2]; };

static __device__ __forceinline__ unsigned short f2b(float f) {
    unsigned u = __builtin_bit_cast(unsigned, f);
    unsigned r = (u + 0x7FFFu + ((u >> 16) & 1u)) >> 16;   // RNE (proven R1/R2/R5/R8)
    return (unsigned short)r;
}
// pack two f32 -> bf16x2 word, software RNE — NOT v_cvt_pk (R6: raw instr != RNE)
static __device__ __forceinline__ unsigned pack2(float lo, float hi) {
    return (unsigned)f2b(lo) | ((unsigned)f2b(hi) << 16);
}

// 16x16x16 bf16 MFMA (gfx950 instruction per ISA §10; proven R14-R26)
static __device__ __forceinline__ f32x4 mfma16(s16x4 a, s16x4 b, f32x4 c) {
#if __has_builtin(__builtin_amdgcn_mfma_f32_16x16x16bf16_1k)
    return __builtin_amdgcn_mfma_f32_16x16x16bf16_1k(a, b, c, 0, 0, 0);
#else
    asm volatile("v_mfma_f32_16x16x16_bf16 %0, %1, %2, %0\n\ts_nop 7\n\ts_nop 7"
                 : "+v"(c) : "v"(a), "v"(b));
    return c;
#endif
}

// K1: fused W-prep + kv-projection + exp + context, all in registers; TWO
// heads/block, K/V phase-split, W in LDS, __launch_bounds__(256,4) (R26).
// R27 change: FLOAT2 POSITION-PAIR LOADS — memory position pos_mem = 2*l15+pt
// (context/sacc are pos-permutation invariant, R19 precedent), so each lane
// loads one float2 per (kc,j) covering BOTH pt fragments: VMEM instrs halve
// (32->16/chunk), 128B/quarter-wave contiguous coalescing, addr VALU halves.
// R26 post-mortem: occupancy bump barely helped -> per-wave MLP is the binder.
__global__ __launch_bounds__(256, 4) void lin_attn_ctx(
    const float* __restrict__ x, const float* __restrict__ Wqkv,
    float* __restrict__ P, int n, int nch)
{
    __shared__ __align__(16) float RED[4224];   // WL (16KB) during loop; Xf/Sf in epilogue

    const int tid = threadIdx.x;
    const int l = tid & 63;
    const int w = tid >> 6;
    const int h0 = blockIdx.x * 2;       // head pair (fastest)
    const int b = blockIdx.y;            // batch
    const int slot = blockIdx.z;         // chunk slot
    const int nslot = gridDim.z;
    const int l15 = l & 15, lg = l >> 4;

    // ---- fused prep_w: 1024 x 16B fragment entries -> LDS ----
    {
        uint4* WL4 = (uint4*)RED;
        for (int e = tid; e < 1024; e += 256) {
            const int lane = e & 63, kc = (e >> 6) & 1, rt = (e >> 7) & 1;
            const int kv = (e >> 8) & 1, hh = e >> 9;
            const int row = 128 + kv * 128 + (2 * (h0 + hh) + rt) * 16 + (lane & 15);
            const float* src = Wqkv + row * 64 + kc * 32 + (lane >> 4) * 8;
            uint4 q;
            q.x = pack2(src[0], src[1]);
            q.y = pack2(src[2], src[3]);
            q.z = pack2(src[4], src[5]);
            q.w = pack2(src[6], src[7]);
            WL4[e] = q;
        }
        __syncthreads();
    }
    const s16x8* WLf = (const s16x8*)RED;

    f32x4 zero4 = {0.f, 0.f, 0.f, 0.f};
    f32x4 ctx[2][2][2];                  // [hh][rt][vt]
    float sacc[2][2] = {{0.f, 0.f}, {0.f, 0.f}};
#pragma unroll
    for (int hh = 0; hh < 2; ++hh)
#pragma unroll
        for (int a = 0; a < 2; ++a)
#pragma unroll
            for (int c2 = 0; c2 < 2; ++c2) ctx[hh][a][c2] = zero4;

    // lane base: positions 2*l15 and 2*l15+1 (pt = low bit)
    const float* xw = x + (size_t)b * CIN * n + w * 32 + 2 * l15;

    for (int ch = slot; ch < nch; ch += nslot) {
        // ---- direct global -> float2 pos-pair loads, pack immediately ----
        const float* xp = xw + ch * NP;
        float2 xv[2][8];                 // [kc][j], .x -> pt0, .y -> pt1
#pragma unroll
        for (int kc = 0; kc < 2; ++kc)
#pragma unroll
            for (int j = 0; j < 8; ++j)
                xv[kc][j] = *(const float2*)(xp + (size_t)(kc * 32 + lg * 8 + j) * n);

        s16x8 bx[2][2];
#pragma unroll
        for (int pt = 0; pt < 2; ++pt)
#pragma unroll
            for (int kc = 0; kc < 2; ++kc) {
                FragU fu;
#pragma unroll
                for (int i = 0; i < 4; ++i)
                    fu.u[i] = pack2(pt ? xv[kc][2 * i].y     : xv[kc][2 * i].x,
                                    pt ? xv[kc][2 * i + 1].y : xv[kc][2 * i + 1].x);
                bx[pt][kc] = fu.v;
            }

#pragma unroll
        for (int hh = 0; hh < 2; ++hh) {
            Frag4 ekf[2][2], vf[2][2];       // [pt][rt]
            // ---- K phase: only ak fragments live ----
            {
                s16x8 ak[2][2];
#pragma unroll
                for (int rt = 0; rt < 2; ++rt)
#pragma unroll
                    for (int kc = 0; kc < 2; ++kc)
                        ak[rt][kc] = WLf[(((hh * 2 + 0) * 2 + rt) * 2 + kc) * 64 + l];
#pragma unroll
                for (int pt = 0; pt < 2; ++pt)
#pragma unroll
                    for (int rt = 0; rt < 2; ++rt) {
                        f32x4 z = zero4;
                        z = __builtin_amdgcn_mfma_f32_16x16x32_bf16(bx[pt][0], ak[rt][0], z, 0, 0, 0);
                        z = __builtin_amdgcn_mfma_f32_16x16x32_bf16(bx[pt][1], ak[rt][1], z, 0, 0, 0);
                        float e0 = __expf(z[0]), e1 = __expf(z[1]);
                        float e2 = __expf(z[2]), e3 = __expf(z[3]);
                        sacc[hh][rt] += (e0 + e1) + (e2 + e3);
                        Frag4 fe; fe.u[0] = pack2(e0, e1); fe.u[1] = pack2(e2, e3);
                        ekf[pt][rt] = fe;
                    }
            }
            __builtin_amdgcn_sched_barrier(0);   // keep av loads out of K phase
            // ---- V phase: only av fragments live ----
            {
                s16x8 av[2][2];
#pragma unroll
                for (int rt = 0; rt < 2; ++rt)
#pragma unroll
                    for (int kc = 0; kc < 2; ++kc)
                        av[rt][kc] = WLf[(((hh * 2 + 1) * 2 + rt) * 2 + kc) * 64 + l];
#pragma unroll
                for (int pt = 0; pt < 2; ++pt)
#pragma unroll
                    for (int rt = 0; rt < 2; ++rt) {
                        f32x4 z2 = zero4;
                        z2 = __builtin_amdgcn_mfma_f32_16x16x32_bf16(bx[pt][0], av[rt][0], z2, 0, 0, 0);
                        z2 = __builtin_amdgcn_mfma_f32_16x16x32_bf16(bx[pt][1], av[rt][1], z2, 0, 0, 0);
                        Frag4 fv; fv.u[0] = pack2(z2[0], z2[1]); fv.u[1] = pack2(z2[2], z2[3]);
                        vf[pt][rt] = fv;
                    }
            }
            // ---- context: ctx[hh][rt][vt] += EK x V^T, K=pos ----
#pragma unroll
            for (int rt = 0; rt < 2; ++rt)
#pragma unroll
                for (int vt = 0; vt < 2; ++vt) {
                    ctx[hh][rt][vt] = mfma16(ekf[0][rt].v, vf[0][vt].v, ctx[hh][rt][vt]);
                    ctx[hh][rt][vt] = mfma16(ekf[1][rt].v, vf[1][vt].v, ctx[hh][rt][vt]);
                }
        }
    }

    // ---- cross-wave reduce, write both heads' partials ----
    float* Xf = RED;
    float* Sf = RED + 4096;
    float* Pb = P + (size_t)(b * nslot + slot) * 4224;
#pragma unroll
    for (int hh = 0; hh < 2; ++hh) {
        const int h = h0 + hh;
        __syncthreads();   // hh=0: all waves exited main loop (WL now dead); hh=1: Xf consumed
#pragma unroll
        for (int rt = 0; rt < 2; ++rt)
#pragma unroll
            for (int vt = 0; vt < 2; ++vt)
#pragma unroll
                for (int r = 0; r < 4; ++r) {
                    int d = rt * 16 + lg * 4 + r, e = vt * 16 + l15;
                    Xf[w * 1024 + d * 32 + e] = ctx[hh][rt][vt][r];
                }
#pragma unroll
        for (int rt = 0; rt < 2; ++rt) {
            float s = sacc[hh][rt];
            s += __shfl_xor(s, 16);
            s += __shfl_xor(s, 32);
            if (l < 16) Sf[w * 32 + rt * 16 + l15] = s;
        }
        __syncthreads();
        for (int i = tid; i < 1024; i += 256)
            Pb[h * 1056 + i] = Xf[i] + Xf[1024 + i] + Xf[2048 + i] + Xf[3072 + i];
        if (tid < 32)
            Pb[h * 1056 + 1024 + tid] = Sf[tid] + Sf[32 + tid] + Sf[64 + tid] + Sf[96 + tid];
    }
}

// K2: slot-sliced partial reduce (FLOAT4): P[b][slot][4224] -> P2[b][16][4224]
__global__ __launch_bounds__(256) void reduce_p1(
    const float* __restrict__ P, float* __restrict__ P2, int nblk)
{
    const int idx4 = blockIdx.x * 256 + threadIdx.x;
    if (idx4 >= 1056) return;            // 4224 / 4
    const int b = blockIdx.z, sz = blockIdx.y;
    const f32x4* P4 = (const f32x4*)P;
    f32x4 acc = {0.f, 0.f, 0.f, 0.f};
    for (int slot = sz; slot < nblk; slot += 16)
        acc += P4[((size_t)(b * nblk + slot)) * 1056 + idx4];
    ((f32x4*)P2)[((size_t)(b * 16 + sz)) * 1056 + idx4] = acc;
}

// K3: final 16-slot reduce (merged) + build Mt[c][o]; (o-slice=8, batch) blocks.
__global__ __launch_bounds__(256) void build_M(
    const float* __restrict__ P2, const float* __restrict__ Wout,
    const float* __restrict__ Wqkv, float* __restrict__ Mt)
{
    __shared__ float Rsh[4224];
    __shared__ float ctx[4096];          // [h][e][d] (transposed)
    __shared__ float Ash[8 * 128];       // A[oo][h*32+d]
    const int b = blockIdx.y;
    const int o0 = blockIdx.x * 8;
    const int tid = threadIdx.x;
    for (int i = tid; i < 4224; i += 256) {
        float acc = 0.f;
#pragma unroll
        for (int s = 0; s < 16; ++s)
            acc += P2[((size_t)(b * 16 + s)) * 4224 + i];
        Rsh[i] = acc;
    }
    __syncthreads();
    for (int i = tid; i < 4096; i += 256) {
        const int hh = i >> 10, rr = i & 1023, e = rr >> 5, d = rr & 31;
        ctx[i] = Rsh[hh * 1056 + d * 32 + e] / Rsh[hh * 1056 + 1024 + d];
    }
    __syncthreads();
    for (int i = tid; i < 1024; i += 256) {
        const int oo = i >> 7, m = i & 127, hh = m >> 5, d = m & 31;
        float acc = 0.f;
#pragma unroll
        for (int e = 0; e < 32; ++e)
            acc += Wout[(o0 + oo) * 128 + hh * 32 + e] * ctx[hh * 1024 + e * 32 + d];
        Ash[i] = acc;
    }
    __syncthreads();
    const float scale = 0.17677669529663687f;
    for (int i = tid; i < 512; i += 256) {
        const int oo = i >> 6, c = i & 63;
        float acc = 0.f;
#pragma unroll
        for (int m = 0; m < 128; ++m)
            acc += Ash[oo * 128 + m] * Wqkv[m * 64 + c];
        Mt[b * 4096 + c * 64 + (o0 + oo)] = acc * scale;   // transposed store
    }
}

// K4: y[b,o,p] = sum_c Mt[c][o] x[b,c,p] + b_out[o] — packed-f32 (v_pk_fma)
__global__ __launch_bounds__(256, 4) void final_proj(
    const float* __restrict__ x, const float* __restrict__ Mt,
    const float* __restrict__ bout, float* __restrict__ y, int n)
{
    const int b = blockIdx.y;
    const int p = blockIdx.x * 256 + threadIdx.x;
    const float* xb = x + (size_t)b * CIN * n + p;
    const float* M = Mt + b * 4096;
    f32x2 acc[32];
#pragma unroll
    for (int o = 0; o < 32; ++o) {
        f32x2 t = { bout[2 * o], bout[2 * o + 1] };
        acc[o] = t;
    }
    for (int c = 0; c < 64; ++c) {
        const float xv = xb[(size_t)c * n];
        f32x2 xv2 = { xv, xv };
        const f32x2* Mr = (const f32x2*)(M + c * 64);
#pragma unroll
        for (int o = 0; o < 32; ++o)
            acc[o] += Mr[o] * xv2;
    }
    float* yb = y + (size_t)b * CIN * n + p;
#pragma unroll
    for (int o = 0; o < 32; ++o) {
        yb[(size_t)(2 * o) * n]     = acc[o][0];
        yb[(size_t)(2 * o + 1) * n] = acc[o][1];
    }
}

extern "C" void kernel_launch(void* const* d_in, const int* in_sizes, int n_in,
                              void* d_out, int out_size, void* d_ws, size_t ws_size,
                              hipStream_t stream) {
    const float* x    = (const float*)d_in[0];
    const float* Wqkv = (const float*)d_in[1];
    const float* Wout = (const float*)d_in[2];
    const float* bout = (const float*)d_in[3];
    float* y = (float*)d_out;

    const int n = in_sizes[0] / 128;   // 110592
    const int nch = n / NP;            // 864

    // ws-adaptive partial-slot count (216 -> 4 chunks/block)
    int BLKX = 216;
    for (;;) {
        size_t need = (size_t)2 * BLKX * 4224 * 4            // P
                    + (size_t)2 * 16 * 4224 * 4              // P2
                    + 2 * 4096 * 4;                          // Mt
        if (need <= ws_size || BLKX <= 64) break;
        BLKX >>= 1;
    }
    float* P  = (float*)d_ws;
    float* P2 = P + (size_t)2 * BLKX * 4224;
    float* Mt = P2 + (size_t)2 * 16 * 4224;

    lin_attn_ctx<<<dim3(2, 2, BLKX), 256, 0, stream>>>(x, Wqkv, P, n, nch);
    reduce_p1<<<dim3(5, 16, 2), 256, 0, stream>>>(P, P2, BLKX);
    build_M<<<dim3(8, 2), 256, 0, stream>>>(P2, Wout, Wqkv, Mt);
    final_proj<<<dim3(n / 256, 2), 256, 0, stream>>>(x, Mt, bout, y, n);
}